// Round 1
// baseline (3610.405 us; speedup 1.0000x reference)
//
#include <hip/hip_runtime.h>

#define NROWS 131072
#define KCB 512
#define DDIM 512
#define BM 32
#define BD 16
#define NT 256

// ---------------------------------------------------------------------------
// pnorm[k] = sum_d P[k][d]^2  (fp32, matches np within ~1e-7)
// ---------------------------------------------------------------------------
__global__ void pnorm_kernel(const float* __restrict__ P, float* __restrict__ pnorm) {
    int k = blockIdx.x * 64 + threadIdx.x;
    if (k >= KCB) return;
    const float4* p4 = (const float4*)P + (size_t)k * (DDIM / 4);
    float s = 0.f;
#pragma unroll 8
    for (int q = 0; q < DDIM / 4; ++q) {
        float4 v = p4[q];
        s += ((v.x * v.x + v.y * v.y) + (v.z * v.z + v.w * v.w));
    }
    pnorm[k] = s;
}

// ---------------------------------------------------------------------------
// Fused fp32 GEMM (z @ P^T) + argmin + gather + blend.
// Block: 256 threads = 8 ty * 32 tx. BM=32 rows/block, all K=512 columns
// held in acc[4][16] per thread (thread (ty,tx): rows ty*4..+3, cols j*32+tx).
// D staged in BD=16 chunks: ps4[k][quad] with row stride 5 float4 (pad)
// so consecutive tx lanes cover all 8 bank-quads; ty-halves broadcast.
// ---------------------------------------------------------------------------
__global__ __launch_bounds__(NT, 2) void vq_kernel(
    const float* __restrict__ z, const float* __restrict__ P,
    const float* __restrict__ pnorm, float* __restrict__ out)
{
    __shared__ float4 ps4[KCB * 5];   // 40 KB: P chunk, [k][quad], stride 5
    __shared__ float4 zs4[BM * 5];    // 2.5 KB: z chunk
    __shared__ float  znorm_s[BM];
    __shared__ float  znp[BM][8];
    __shared__ float  pn_s[KCB];
    __shared__ float  redv[BM * 32];
    __shared__ int    redi[BM * 32];
    __shared__ int    sidx[BM];

    const int tid = threadIdx.x;
    const int tx = tid & 31;
    const int ty = tid >> 5;
    const int n0 = blockIdx.x * BM;
    const float4* Z4 = (const float4*)z;
    const float4* P4 = (const float4*)P;

    // stage pnorm into LDS
    for (int i = tid; i < KCB; i += NT) pn_s[i] = pnorm[i];

    // znorm: 8 threads per row, 64 d's each, then sequential combine
    {
        int row = tid >> 3, seg = tid & 7;
        const float4* zp = Z4 + (size_t)(n0 + row) * (DDIM / 4) + seg * 16;
        float s = 0.f;
#pragma unroll
        for (int u = 0; u < 16; ++u) {
            float4 v = zp[u];
            s += ((v.x * v.x + v.y * v.y) + (v.z * v.z + v.w * v.w));
        }
        znp[row][seg] = s;
    }
    __syncthreads();
    if (tid < BM) {
        float s = 0.f;
        for (int j = 0; j < 8; ++j) s += znp[tid][j];
        znorm_s[tid] = s;
    }

    float acc[4][16];
#pragma unroll
    for (int r = 0; r < 4; ++r)
#pragma unroll
        for (int c = 0; c < 16; ++c) acc[r][c] = 0.f;

    // prefetch chunk 0 into registers
    float4 pf[8];
    float4 zf;
#pragma unroll
    for (int t = 0; t < 8; ++t) {
        int i = tid + NT * t;
        pf[t] = P4[(size_t)(i >> 2) * (DDIM / 4) + (i & 3)];
    }
    if (tid < BM * 4) zf = Z4[(size_t)(n0 + (tid >> 2)) * (DDIM / 4) + (tid & 3)];

    for (int d0 = 0; d0 < DDIM; d0 += BD) {
        __syncthreads();   // protect ps4/zs4 (and first-iter znorm_s/pn_s)
#pragma unroll
        for (int t = 0; t < 8; ++t) {
            int i = tid + NT * t;
            ps4[(i >> 2) * 5 + (i & 3)] = pf[t];
        }
        if (tid < BM * 4) zs4[(tid >> 2) * 5 + (tid & 3)] = zf;
        __syncthreads();

        // prefetch next chunk (overlaps with FMAs below)
        if (d0 + BD < DDIM) {
            const int dq0 = (d0 + BD) >> 2;
#pragma unroll
            for (int t = 0; t < 8; ++t) {
                int i = tid + NT * t;
                pf[t] = P4[(size_t)(i >> 2) * (DDIM / 4) + dq0 + (i & 3)];
            }
            if (tid < BM * 4)
                zf = Z4[(size_t)(n0 + (tid >> 2)) * (DDIM / 4) + dq0 + (tid & 3)];
        }

        // compute: 1024 FMAs per thread per chunk, strict ascending-d order
#pragma unroll
        for (int q = 0; q < 4; ++q) {
            float4 zr[4];
#pragma unroll
            for (int r = 0; r < 4; ++r) zr[r] = zs4[(ty * 4 + r) * 5 + q];
#pragma unroll
            for (int j = 0; j < 16; ++j) {
                float4 pv = ps4[(j * 32 + tx) * 5 + q];
#pragma unroll
                for (int r = 0; r < 4; ++r) {
                    acc[r][j] += zr[r].x * pv.x;
                    acc[r][j] += zr[r].y * pv.y;
                    acc[r][j] += zr[r].z * pv.z;
                    acc[r][j] += zr[r].w * pv.w;
                }
            }
        }
    }

    // per-thread argmin over its 16 columns (k = j*32+tx, ascending j)
    {
        int row0 = ty * 4;
#pragma unroll
        for (int r = 0; r < 4; ++r) {
            float zn = znorm_s[row0 + r];
            float bvr = 0.f;
            int bir = 0;
#pragma unroll
            for (int j = 0; j < 16; ++j) {
                int k = j * 32 + tx;
                float t1 = zn + pn_s[k];           // fp32(A+B), like np
                float dist = t1 - 2.0f * acc[r][j]; // 2*acc exact, one rounding
                if (j == 0 || dist < bvr) { bvr = dist; bir = k; }
            }
            redv[(row0 + r) * 32 + tx] = bvr;
            redi[(row0 + r) * 32 + tx] = bir;
        }
    }
    __syncthreads();

    // cross-thread reduce: lexicographic (val, idx) == np.argmin first-min
    if (tid < BM) {
        float bv = redv[tid * 32];
        int bi = redi[tid * 32];
        for (int t = 1; t < 32; ++t) {
            float v = redv[tid * 32 + t];
            int ix = redi[tid * 32 + t];
            if (v < bv || (v == bv && ix < bi)) { bv = v; bi = ix; }
        }
        sidx[tid] = bi;
        out[(size_t)2 * NROWS * DDIM + n0 + tid] = (float)bi;  // indices as f32
    }
    __syncthreads();

    // gather z_tilde = P[idx], blend z_hat = 0.7 z + 0.3 z_tilde
    float4* outh = (float4*)out;
    float4* outt = (float4*)out + (size_t)NROWS * (DDIM / 4);
    for (int i = tid; i < BM * (DDIM / 4); i += NT) {
        int row = i >> 7, q = i & 127;
        int kk = sidx[row];
        float4 pv = P4[(size_t)kk * (DDIM / 4) + q];
        float4 zv = Z4[(size_t)(n0 + row) * (DDIM / 4) + q];
        float4 zh;
        zh.x = 0.7f * zv.x + 0.3f * pv.x;
        zh.y = 0.7f * zv.y + 0.3f * pv.y;
        zh.z = 0.7f * zv.z + 0.3f * pv.z;
        zh.w = 0.7f * zv.w + 0.3f * pv.w;
        size_t o = (size_t)(n0 + row) * (DDIM / 4) + q;
        outh[o] = zh;
        outt[o] = pv;
    }
}

extern "C" void kernel_launch(void* const* d_in, const int* in_sizes, int n_in,
                              void* d_out, int out_size, void* d_ws, size_t ws_size,
                              hipStream_t stream) {
    const float* z = (const float*)d_in[0];
    const float* P = (const float*)d_in[1];
    float* pnorm = (float*)d_ws;   // 512 floats of scratch

    pnorm_kernel<<<dim3(KCB / 64), dim3(64), 0, stream>>>(P, pnorm);
    vq_kernel<<<dim3(NROWS / BM), dim3(NT), 0, stream>>>(z, P, pnorm, (float*)d_out);
}